// Round 2
// baseline (14702.666 us; speedup 1.0000x reference)
//
#include <hip/hip_runtime.h>

// LSTM T=1000 N=32 D=320 H=1024 L=3 on MI355X — weight-stationary persistent kernel.
// One cooperative launch; 192 blocks = 3 layers x 64 j-tiles, 512 threads = 8 waves.
// Each wave keeps its MFMA B-fragments (128 VGPRs) in registers for the whole run.
// Grid sync per wavefront step via device-scope atomic barrier (release/acquire).
//
// ws layout (bytes):
//   [0,         20480000)  x as bf16                (T*N*320)
//   [20480000,  66617344)  packed B fragments       (23,068,672 bf16; l0 K padded to 1536)
//   [66617344,  67010560)  h ping-pong bf16         (L * 2 * N*H)
//   [67010560,  67403776)  c state fp32             (L * N*H)
//   [67403776,  67452928)  bias fp32                (L * 4096)
//   [67452928,  67452992)  barrier counter

#define T_ 1000
#define N_ 32
#define D_ 320
#define H_ 1024
#define NH (N_ * H_)
#define NBLK 192

typedef __bf16 bf16;
typedef bf16 bf16x8 __attribute__((ext_vector_type(8)));
typedef bf16 bf16x4 __attribute__((ext_vector_type(4)));
typedef float floatx4 __attribute__((ext_vector_type(4)));

__device__ __forceinline__ float sigm(float x) { return 1.f / (1.f + __expf(-x)); }
__device__ __forceinline__ float tanh_(float x) {
  float e = __expf(2.f * x);
  return 1.f - 2.f / (e + 1.f);
}

// ---- prep: x (fp32) -> bf16 ----
__global__ __launch_bounds__(256) void prep_x(const float4* __restrict__ x,
                                              bf16x4* __restrict__ xb) {
  int idx = blockIdx.x * 256 + threadIdx.x;
  float4 v = x[idx];
  bf16x4 o;
  o[0] = (bf16)v.x; o[1] = (bf16)v.y; o[2] = (bf16)v.z; o[3] = (bf16)v.w;
  xb[idx] = o;
}

// ---- prep: pack W = [w_ih_l ; w_hh_l] into MFMA B-fragment order.
// within-layer idx = ((g*64 + jt)*KB + kb)*512 + lane*8 + i
//   k = kb*32 + (lane>>4)*8 + i ; j = g*1024 + jt*16 + (lane&15)
// l=0 KB=48 (K padded 1344->1536 with zeros); l>=1 KB=64.
__global__ __launch_bounds__(256) void prep_pack(const float* __restrict__ w_ih0,
                                                 const float* __restrict__ w_ihr,
                                                 const float* __restrict__ w_hh,
                                                 bf16* __restrict__ packed) {
  int idx = blockIdx.x * 256 + threadIdx.x;  // 23,068,672 total
  int l, r;
  if (idx < 6291456)       { l = 0; r = idx; }
  else if (idx < 14680064) { l = 1; r = idx - 6291456; }
  else                     { l = 2; r = idx - 14680064; }
  const int i    = r & 7;
  const int lane = (r >> 3) & 63;
  const int q    = r >> 9;
  int kb, p;
  if (l == 0) { kb = q % 48; p = q / 48; }
  else        { kb = q & 63; p = q >> 6; }
  const int jt = p & 63;
  const int g  = p >> 6;
  const int k  = kb * 32 + ((lane >> 4) << 3) + i;
  const int j  = (g << 10) + jt * 16 + (lane & 15);
  const int KX = (l == 0) ? 320 : 1024;
  const int KR = (l == 0) ? 1344 : 2048;
  float v;
  if (k >= KR) {
    v = 0.f;  // zero padding (l=0 only)
  } else if (k < KX) {
    v = (l == 0) ? w_ih0[(size_t)k * 4096 + j]
                 : w_ihr[(size_t)(l - 1) * 4194304 + (size_t)k * 4096 + j];
  } else {
    v = w_hh[(size_t)l * 4194304 + (size_t)(k - KX) * 4096 + j];
  }
  packed[idx] = (bf16)v;
}

// ---- prep: h0 -> slot 1, c0, bias sum, barrier counter = 0
__global__ __launch_bounds__(256) void prep_state(const float* __restrict__ h0,
                                                  const float* __restrict__ c0,
                                                  const float* __restrict__ b_ih,
                                                  const float* __restrict__ b_hh,
                                                  bf16* __restrict__ hbuf,
                                                  float* __restrict__ c_state,
                                                  float* __restrict__ bias,
                                                  unsigned int* __restrict__ bar) {
  int idx = blockIdx.x * 256 + threadIdx.x;  // 98,304 threads
  int l = idx >> 15;
  int rem = idx & 32767;
  hbuf[(size_t)l * 2 * NH + NH + rem] = (bf16)h0[idx];
  c_state[idx] = c0[idx];
  if (idx < 12288) bias[idx] = b_ih[idx] + b_hh[idx];
  if (idx == 0) *bar = 0u;
}

// ---- persistent wavefront kernel ----
__global__ __launch_bounds__(512, 2) void lstm_persist(
    const bf16* __restrict__ xb, const bf16* __restrict__ packed,
    bf16* __restrict__ hbuf, float* __restrict__ c_state,
    const float* __restrict__ bias, float* __restrict__ out,
    unsigned int* __restrict__ bar) {
  const int b  = blockIdx.x;
  const int l  = b >> 6;
  const int jt = b & 63;
  const int tid  = threadIdx.x;
  const int wid  = tid >> 6;
  const int lane = tid & 63;
  const int quad = lane >> 4;
  const int lo   = lane & 15;

  const int KBp  = (l == 0) ? 48 : 64;     // padded K blocks
  const int KBW  = KBp >> 3;               // kb per wave: 6 or 8
  const int KXb  = (l == 0) ? 10 : 32;     // x-region kb count
  const int xstr = (l == 0) ? D_ : H_;
  const size_t lbase = (l == 0) ? 0u : (l == 1 ? 6291456u : 14680064u);
  const int gstr = 64 * KBp * 512;
  const bf16* Bb = packed + lbase + (size_t)jt * KBp * 512;

  // ---- load this wave's weights into registers (held for entire run) ----
  bf16x8 W[4][8];
  {
    bf16x8 z;
#pragma unroll
    for (int i = 0; i < 8; ++i) z[i] = (bf16)0.f;
#pragma unroll
    for (int g = 0; g < 4; ++g)
#pragma unroll
      for (int s = 0; s < 8; ++s) {
        if (s < KBW) {
          const int kb = wid + (s << 3);
          W[g][s] = *(const bf16x8*)(Bb + (size_t)g * gstr + (size_t)kb * 512 + lane * 8);
        } else {
          W[g][s] = z;
        }
      }
  }

  // per-thread epilogue constants: thread handles output (m, col)
  const int m   = tid >> 4;
  const int col = tid & 15;
  const int mt_ = m >> 4;
  const int qq  = (m >> 2) & 3;
  const int rr  = m & 3;
  const int lp  = qq * 16 + col;
  const int j_h = jt * 16 + col;
  const float bI = bias[l * 4096 + j_h];
  const float bF = bias[l * 4096 + 1024 + j_h];
  const float bG = bias[l * 4096 + 2048 + j_h];
  const float bO = bias[l * 4096 + 3072 + j_h];
  float* cst = c_state + l * NH;
  const int off = m * H_ + j_h;

  const int ax0 = lo * xstr + quad * 8;
  const int ax1 = (16 + lo) * xstr + quad * 8;
  const int ah0 = lo * H_ + quad * 8;
  const int ah1 = (16 + lo) * H_ + quad * 8;

  __shared__ floatx4 red4[8][2][4][64];  // [wave][mt][gate][lane] = 64 KB
  const float* rbase = (const float*)red4;

  for (int wv = 0; wv < T_ + 2; ++wv) {
    const int t = wv - l;
    if (t >= 0 && t < T_) {
      const bf16* xsrc = (l == 0)
          ? xb + (size_t)t * (N_ * D_)
          : hbuf + (size_t)(l - 1) * 2 * NH + (size_t)(t & 1) * NH;
      const bf16* hsrc = hbuf + (size_t)l * 2 * NH + (size_t)((t - 1) & 1) * NH;

      floatx4 acc[2][4];
      const floatx4 zero = {0.f, 0.f, 0.f, 0.f};
#pragma unroll
      for (int mt = 0; mt < 2; ++mt)
#pragma unroll
        for (int g = 0; g < 4; ++g) acc[mt][g] = zero;

#pragma unroll
      for (int s = 0; s < 8; ++s) {
        if (s < KBW) {
          const int kb = wid + (s << 3);
          const bool inx = (kb < KXb);
          const bf16* pa = inx ? (xsrc + (size_t)kb * 32)
                               : (hsrc + (size_t)(kb - KXb) * 32);
          const bf16x8 a0 = *(const bf16x8*)(pa + (inx ? ax0 : ah0));
          const bf16x8 a1 = *(const bf16x8*)(pa + (inx ? ax1 : ah1));
          acc[0][0] = __builtin_amdgcn_mfma_f32_16x16x32_bf16(a0, W[0][s], acc[0][0], 0, 0, 0);
          acc[0][1] = __builtin_amdgcn_mfma_f32_16x16x32_bf16(a0, W[1][s], acc[0][1], 0, 0, 0);
          acc[0][2] = __builtin_amdgcn_mfma_f32_16x16x32_bf16(a0, W[2][s], acc[0][2], 0, 0, 0);
          acc[0][3] = __builtin_amdgcn_mfma_f32_16x16x32_bf16(a0, W[3][s], acc[0][3], 0, 0, 0);
          acc[1][0] = __builtin_amdgcn_mfma_f32_16x16x32_bf16(a1, W[0][s], acc[1][0], 0, 0, 0);
          acc[1][1] = __builtin_amdgcn_mfma_f32_16x16x32_bf16(a1, W[1][s], acc[1][1], 0, 0, 0);
          acc[1][2] = __builtin_amdgcn_mfma_f32_16x16x32_bf16(a1, W[2][s], acc[1][2], 0, 0, 0);
          acc[1][3] = __builtin_amdgcn_mfma_f32_16x16x32_bf16(a1, W[3][s], acc[1][3], 0, 0, 0);
        }
      }

      // K-split reduction: stash partials, then 1 thread = 1 output element.
#pragma unroll
      for (int mt = 0; mt < 2; ++mt)
#pragma unroll
        for (int g = 0; g < 4; ++g) red4[wid][mt][g][lane] = acc[mt][g];
      __syncthreads();

      float s0 = 0.f, s1 = 0.f, s2 = 0.f, s3 = 0.f;
#pragma unroll
      for (int w = 0; w < 8; ++w) {
        const int base = (w * 2 + mt_) * 1024 + lp * 4 + rr;
        s0 += rbase[base];
        s1 += rbase[base + 256];
        s2 += rbase[base + 512];
        s3 += rbase[base + 768];
      }
      const float ii = sigm(s0 + bI);
      const float ff = sigm(s1 + bF);
      const float gg = tanh_(s2 + bG);
      const float oo = sigm(s3 + bO);
      const float c = ff * cst[off] + ii * gg;
      cst[off] = c;
      const float h = oo * tanh_(c);
      bf16* hdst = hbuf + (size_t)l * 2 * NH + (size_t)(t & 1) * NH;
      hdst[off] = (bf16)h;
      if (l == 2) out[(size_t)t * NH + off] = h;
      if (t == T_ - 1) {
        out[32768000u + l * NH + off] = h;
        out[32866304u + l * NH + off] = c;
      }
    }

    // ---- grid barrier (device-scope release -> spin -> acquire) ----
    __syncthreads();
    if (tid == 0) {
      __hip_atomic_fetch_add(bar, 1u, __ATOMIC_RELEASE, __HIP_MEMORY_SCOPE_AGENT);
      const unsigned int tgt = (unsigned int)(NBLK * (wv + 1));
      while (__hip_atomic_load(bar, __ATOMIC_RELAXED, __HIP_MEMORY_SCOPE_AGENT) < tgt)
        __builtin_amdgcn_s_sleep(2);
      __builtin_amdgcn_fence(__ATOMIC_ACQUIRE, "agent");
    }
    __syncthreads();
  }
}

extern "C" void kernel_launch(void* const* d_in, const int* in_sizes, int n_in,
                              void* d_out, int out_size, void* d_ws, size_t ws_size,
                              hipStream_t stream) {
  (void)in_sizes; (void)n_in; (void)out_size; (void)ws_size;
  const float* x     = (const float*)d_in[0];
  const float* h0    = (const float*)d_in[1];
  const float* c0    = (const float*)d_in[2];
  const float* w_ih0 = (const float*)d_in[3];
  const float* w_ihr = (const float*)d_in[4];
  const float* w_hh  = (const float*)d_in[5];
  const float* b_ih  = (const float*)d_in[6];
  const float* b_hh  = (const float*)d_in[7];
  float* out = (float*)d_out;
  char* ws = (char*)d_ws;

  bf16*  xb      = (bf16*)(ws + 0);
  bf16*  packed  = (bf16*)(ws + 20480000);
  bf16*  hbuf    = (bf16*)(ws + 66617344);
  float* c_state = (float*)(ws + 67010560);
  float* bias    = (float*)(ws + 67403776);
  unsigned int* bar = (unsigned int*)(ws + 67452928);

  hipLaunchKernelGGL(prep_x, dim3(10000), dim3(256), 0, stream,
                     (const float4*)x, (bf16x4*)xb);
  hipLaunchKernelGGL(prep_pack, dim3(90112), dim3(256), 0, stream,
                     w_ih0, w_ihr, w_hh, packed);
  hipLaunchKernelGGL(prep_state, dim3(384), dim3(256), 0, stream,
                     h0, c0, b_ih, b_hh, hbuf, c_state, bias, bar);

  const bf16* xb_c = xb;
  const bf16* packed_c = packed;
  const float* bias_c = bias;
  void* args[] = {(void*)&xb_c, (void*)&packed_c, (void*)&hbuf, (void*)&c_state,
                  (void*)&bias_c, (void*)&out, (void*)&bar};
  hipLaunchCooperativeKernel((const void*)lstm_persist, dim3(NBLK), dim3(512),
                             args, 0, stream);
}

// Round 3
// 14628.848 us; speedup vs baseline: 1.0050x; 1.0050x over previous
//
#include <hip/hip_runtime.h>

// LSTM T=1000 N=32 D=320 H=1024 L=3 on MI355X — weight-stationary persistent kernel.
// One cooperative launch; 192 blocks = 3 layers x 64 j-tiles, 512 threads = 8 waves.
// Each wave keeps its MFMA B-fragments (128 VGPRs) in registers for the whole run.
// R3 fix: __launch_bounds__(512,1) — grid is 1 block/CU, so allow 256 VGPR/thread.
// R2's (512,2) capped VGPRs at 128 < the 128-VGPR weight array + acc -> weights
// were reloaded from memory every step (VGPR_Count=120, FETCH 2GB/dispatch).
//
// ws layout (bytes):
//   [0,         20480000)  x as bf16                (T*N*320)
//   [20480000,  66617344)  packed B fragments       (23,068,672 bf16; l0 K padded to 1536)
//   [66617344,  67010560)  h ping-pong bf16         (L * 2 * N*H)
//   [67010560,  67403776)  c state fp32             (L * N*H)
//   [67403776,  67452928)  bias fp32                (L * 4096)
//   [67452928,  67452992)  barrier counter

#define T_ 1000
#define N_ 32
#define D_ 320
#define H_ 1024
#define NH (N_ * H_)
#define NBLK 192

typedef __bf16 bf16;
typedef bf16 bf16x8 __attribute__((ext_vector_type(8)));
typedef bf16 bf16x4 __attribute__((ext_vector_type(4)));
typedef float floatx4 __attribute__((ext_vector_type(4)));

__device__ __forceinline__ float sigm(float x) { return 1.f / (1.f + __expf(-x)); }
__device__ __forceinline__ float tanh_(float x) {
  float e = __expf(2.f * x);
  return 1.f - 2.f / (e + 1.f);
}

// ---- prep: x (fp32) -> bf16 ----
__global__ __launch_bounds__(256) void prep_x(const float4* __restrict__ x,
                                              bf16x4* __restrict__ xb) {
  int idx = blockIdx.x * 256 + threadIdx.x;
  float4 v = x[idx];
  bf16x4 o;
  o[0] = (bf16)v.x; o[1] = (bf16)v.y; o[2] = (bf16)v.z; o[3] = (bf16)v.w;
  xb[idx] = o;
}

// ---- prep: pack W = [w_ih_l ; w_hh_l] into MFMA B-fragment order.
// within-layer idx = ((g*64 + jt)*KB + kb)*512 + lane*8 + i
//   k = kb*32 + (lane>>4)*8 + i ; j = g*1024 + jt*16 + (lane&15)
// l=0 KB=48 (K padded 1344->1536 with zeros); l>=1 KB=64.
__global__ __launch_bounds__(256) void prep_pack(const float* __restrict__ w_ih0,
                                                 const float* __restrict__ w_ihr,
                                                 const float* __restrict__ w_hh,
                                                 bf16* __restrict__ packed) {
  int idx = blockIdx.x * 256 + threadIdx.x;  // 23,068,672 total
  int l, r;
  if (idx < 6291456)       { l = 0; r = idx; }
  else if (idx < 14680064) { l = 1; r = idx - 6291456; }
  else                     { l = 2; r = idx - 14680064; }
  const int i    = r & 7;
  const int lane = (r >> 3) & 63;
  const int q    = r >> 9;
  int kb, p;
  if (l == 0) { kb = q % 48; p = q / 48; }
  else        { kb = q & 63; p = q >> 6; }
  const int jt = p & 63;
  const int g  = p >> 6;
  const int k  = kb * 32 + ((lane >> 4) << 3) + i;
  const int j  = (g << 10) + jt * 16 + (lane & 15);
  const int KX = (l == 0) ? 320 : 1024;
  const int KR = (l == 0) ? 1344 : 2048;
  float v;
  if (k >= KR) {
    v = 0.f;  // zero padding (l=0 only)
  } else if (k < KX) {
    v = (l == 0) ? w_ih0[(size_t)k * 4096 + j]
                 : w_ihr[(size_t)(l - 1) * 4194304 + (size_t)k * 4096 + j];
  } else {
    v = w_hh[(size_t)l * 4194304 + (size_t)(k - KX) * 4096 + j];
  }
  packed[idx] = (bf16)v;
}

// ---- prep: h0 -> slot 1, c0, bias sum, barrier counter = 0
__global__ __launch_bounds__(256) void prep_state(const float* __restrict__ h0,
                                                  const float* __restrict__ c0,
                                                  const float* __restrict__ b_ih,
                                                  const float* __restrict__ b_hh,
                                                  bf16* __restrict__ hbuf,
                                                  float* __restrict__ c_state,
                                                  float* __restrict__ bias,
                                                  unsigned int* __restrict__ bar) {
  int idx = blockIdx.x * 256 + threadIdx.x;  // 98,304 threads
  int l = idx >> 15;
  int rem = idx & 32767;
  hbuf[(size_t)l * 2 * NH + NH + rem] = (bf16)h0[idx];
  c_state[idx] = c0[idx];
  if (idx < 12288) bias[idx] = b_ih[idx] + b_hh[idx];
  if (idx == 0) *bar = 0u;
}

// ---- persistent wavefront kernel ----
__global__ __launch_bounds__(512, 1) void lstm_persist(
    const bf16* __restrict__ xb, const bf16* __restrict__ packed,
    bf16* __restrict__ hbuf, float* __restrict__ c_state,
    const float* __restrict__ bias, float* __restrict__ out,
    unsigned int* __restrict__ bar) {
  const int b  = blockIdx.x;
  const int l  = b >> 6;
  const int jt = b & 63;
  const int tid  = threadIdx.x;
  const int wid  = tid >> 6;
  const int lane = tid & 63;
  const int quad = lane >> 4;
  const int lo   = lane & 15;

  const int KBp  = (l == 0) ? 48 : 64;     // padded K blocks
  const int KBW  = KBp >> 3;               // kb per wave: 6 or 8
  const int KXb  = (l == 0) ? 10 : 32;     // x-region kb count
  const int xstr = (l == 0) ? D_ : H_;
  const size_t lbase = (l == 0) ? 0u : (l == 1 ? 6291456u : 14680064u);
  const int gstr = 64 * KBp * 512;
  const bf16* Bb = packed + lbase + (size_t)jt * KBp * 512;

  // ---- load this wave's weights into registers (held for entire run) ----
  bf16x8 W[4][8];
  {
    bf16x8 z;
#pragma unroll
    for (int i = 0; i < 8; ++i) z[i] = (bf16)0.f;
#pragma unroll
    for (int g = 0; g < 4; ++g)
#pragma unroll
      for (int s = 0; s < 8; ++s) {
        if (s < KBW) {
          const int kb = wid + (s << 3);
          W[g][s] = *(const bf16x8*)(Bb + (size_t)g * gstr + (size_t)kb * 512 + lane * 8);
        } else {
          W[g][s] = z;
        }
      }
  }

  // per-thread epilogue constants: thread handles output (m, col)
  const int m   = tid >> 4;
  const int col = tid & 15;
  const int mt_ = m >> 4;
  const int qq  = (m >> 2) & 3;
  const int rr  = m & 3;
  const int lp  = qq * 16 + col;
  const int j_h = jt * 16 + col;
  const float bI = bias[l * 4096 + j_h];
  const float bF = bias[l * 4096 + 1024 + j_h];
  const float bG = bias[l * 4096 + 2048 + j_h];
  const float bO = bias[l * 4096 + 3072 + j_h];
  float* cst = c_state + l * NH;
  const int off = m * H_ + j_h;

  const int ax0 = lo * xstr + quad * 8;
  const int ax1 = (16 + lo) * xstr + quad * 8;
  const int ah0 = lo * H_ + quad * 8;
  const int ah1 = (16 + lo) * H_ + quad * 8;

  __shared__ floatx4 red4[8][2][4][64];  // [wave][mt][gate][lane] = 64 KB
  const float* rbase = (const float*)red4;

  for (int wv = 0; wv < T_ + 2; ++wv) {
    const int t = wv - l;
    if (t >= 0 && t < T_) {
      const bf16* xsrc = (l == 0)
          ? xb + (size_t)t * (N_ * D_)
          : hbuf + (size_t)(l - 1) * 2 * NH + (size_t)(t & 1) * NH;
      const bf16* hsrc = hbuf + (size_t)l * 2 * NH + (size_t)((t - 1) & 1) * NH;

      floatx4 acc[2][4];
      const floatx4 zero = {0.f, 0.f, 0.f, 0.f};
#pragma unroll
      for (int mt = 0; mt < 2; ++mt)
#pragma unroll
        for (int g = 0; g < 4; ++g) acc[mt][g] = zero;

#pragma unroll
      for (int s = 0; s < 8; ++s) {
        if (s < KBW) {
          const int kb = wid + (s << 3);
          const bool inx = (kb < KXb);
          const bf16* pa = inx ? (xsrc + (size_t)kb * 32)
                               : (hsrc + (size_t)(kb - KXb) * 32);
          const bf16x8 a0 = *(const bf16x8*)(pa + (inx ? ax0 : ah0));
          const bf16x8 a1 = *(const bf16x8*)(pa + (inx ? ax1 : ah1));
          acc[0][0] = __builtin_amdgcn_mfma_f32_16x16x32_bf16(a0, W[0][s], acc[0][0], 0, 0, 0);
          acc[0][1] = __builtin_amdgcn_mfma_f32_16x16x32_bf16(a0, W[1][s], acc[0][1], 0, 0, 0);
          acc[0][2] = __builtin_amdgcn_mfma_f32_16x16x32_bf16(a0, W[2][s], acc[0][2], 0, 0, 0);
          acc[0][3] = __builtin_amdgcn_mfma_f32_16x16x32_bf16(a0, W[3][s], acc[0][3], 0, 0, 0);
          acc[1][0] = __builtin_amdgcn_mfma_f32_16x16x32_bf16(a1, W[0][s], acc[1][0], 0, 0, 0);
          acc[1][1] = __builtin_amdgcn_mfma_f32_16x16x32_bf16(a1, W[1][s], acc[1][1], 0, 0, 0);
          acc[1][2] = __builtin_amdgcn_mfma_f32_16x16x32_bf16(a1, W[2][s], acc[1][2], 0, 0, 0);
          acc[1][3] = __builtin_amdgcn_mfma_f32_16x16x32_bf16(a1, W[3][s], acc[1][3], 0, 0, 0);
        }
      }

      // K-split reduction: stash partials, then 1 thread = 1 output element.
#pragma unroll
      for (int mt = 0; mt < 2; ++mt)
#pragma unroll
        for (int g = 0; g < 4; ++g) red4[wid][mt][g][lane] = acc[mt][g];
      __syncthreads();

      float s0 = 0.f, s1 = 0.f, s2 = 0.f, s3 = 0.f;
#pragma unroll
      for (int w = 0; w < 8; ++w) {
        const int base = (w * 2 + mt_) * 1024 + lp * 4 + rr;
        s0 += rbase[base];
        s1 += rbase[base + 256];
        s2 += rbase[base + 512];
        s3 += rbase[base + 768];
      }
      const float ii = sigm(s0 + bI);
      const float ff = sigm(s1 + bF);
      const float gg = tanh_(s2 + bG);
      const float oo = sigm(s3 + bO);
      const float c = ff * cst[off] + ii * gg;
      cst[off] = c;
      const float h = oo * tanh_(c);
      bf16* hdst = hbuf + (size_t)l * 2 * NH + (size_t)(t & 1) * NH;
      hdst[off] = (bf16)h;
      if (l == 2) out[(size_t)t * NH + off] = h;
      if (t == T_ - 1) {
        out[32768000u + l * NH + off] = h;
        out[32866304u + l * NH + off] = c;
      }
    }

    // ---- grid barrier (device-scope release -> spin -> acquire) ----
    __syncthreads();
    if (tid == 0) {
      __hip_atomic_fetch_add(bar, 1u, __ATOMIC_RELEASE, __HIP_MEMORY_SCOPE_AGENT);
      const unsigned int tgt = (unsigned int)(NBLK * (wv + 1));
      while (__hip_atomic_load(bar, __ATOMIC_RELAXED, __HIP_MEMORY_SCOPE_AGENT) < tgt)
        __builtin_amdgcn_s_sleep(2);
      __builtin_amdgcn_fence(__ATOMIC_ACQUIRE, "agent");
    }
    __syncthreads();
  }
}

extern "C" void kernel_launch(void* const* d_in, const int* in_sizes, int n_in,
                              void* d_out, int out_size, void* d_ws, size_t ws_size,
                              hipStream_t stream) {
  (void)in_sizes; (void)n_in; (void)out_size; (void)ws_size;
  const float* x     = (const float*)d_in[0];
  const float* h0    = (const float*)d_in[1];
  const float* c0    = (const float*)d_in[2];
  const float* w_ih0 = (const float*)d_in[3];
  const float* w_ihr = (const float*)d_in[4];
  const float* w_hh  = (const float*)d_in[5];
  const float* b_ih  = (const float*)d_in[6];
  const float* b_hh  = (const float*)d_in[7];
  float* out = (float*)d_out;
  char* ws = (char*)d_ws;

  bf16*  xb      = (bf16*)(ws + 0);
  bf16*  packed  = (bf16*)(ws + 20480000);
  bf16*  hbuf    = (bf16*)(ws + 66617344);
  float* c_state = (float*)(ws + 67010560);
  float* bias    = (float*)(ws + 67403776);
  unsigned int* bar = (unsigned int*)(ws + 67452928);

  hipLaunchKernelGGL(prep_x, dim3(10000), dim3(256), 0, stream,
                     (const float4*)x, (bf16x4*)xb);
  hipLaunchKernelGGL(prep_pack, dim3(90112), dim3(256), 0, stream,
                     w_ih0, w_ihr, w_hh, packed);
  hipLaunchKernelGGL(prep_state, dim3(384), dim3(256), 0, stream,
                     h0, c0, b_ih, b_hh, hbuf, c_state, bias, bar);

  const bf16* xb_c = xb;
  const bf16* packed_c = packed;
  const float* bias_c = bias;
  void* args[] = {(void*)&xb_c, (void*)&packed_c, (void*)&hbuf, (void*)&c_state,
                  (void*)&bias_c, (void*)&out, (void*)&bar};
  hipLaunchCooperativeKernel((const void*)lstm_persist, dim3(NBLK), dim3(512),
                             args, 0, stream);
}